// Round 15
// baseline (71.191 us; speedup 1.0000x reference)
//
#include <hip/hip_runtime.h>
#include <hip/hip_fp16.h>
#include <math.h>

#define SEQ 250
#define ST  252      // padded t-stride: rows 16B-aligned (ST*4 = 1008 = 63*16)
#define NCLS 12

typedef __attribute__((ext_vector_type(4))) _Float16 half4v;
typedef __attribute__((ext_vector_type(4))) float    float4v;

// Butterfly add via DPP (zero DS-pipe ops).
// 0xB1=quad_perm xor1; 0x4E=quad_perm xor2 (both quad-local).
template<int CTRL>
__device__ __forceinline__ float dpp_add(float v) {
    int t = __builtin_amdgcn_update_dpp(0, __float_as_int(v), CTRL, 0xF, 0xF, true);
    return v + __int_as_float(t);
}

__device__ __forceinline__ __half2 f_as_h2(float f) {
    union { float f; __half2 h; } u; u.f = f; return u.h;
}
__device__ __forceinline__ float h2_as_f(__half2 h) {
    union { __half2 h; float f; } u; u.h = h; return u.f;
}

// 512 threads, TWO batch elements per block.
// LDS: 2 x (s_bc 16128 + s_dlu 16128 + s_sz 8064) = 80,640 B -> 2 blocks/CU.
// r4-r6: no register live ranges across the scan (spills -> 45 MB scratch).
// r11/r12: matrix pipe takes the x_proj projection (ph3).
// r13: ph1-MFMA regressed (gather+cvt overhead) -> ph1/ph2 stay scalar.
// r15: scan fold-4 (1 wave/problem, 4 states/lane, 2-stage quad DPP reduce)
//      with explicit 2-deep software pipeline (loads hoisted above the
//      aliasing y-stores in program order).
__global__ __launch_bounds__(512)
void mamba_cls_kernel(
    const float* __restrict__ x,         // (B, 8, 250)
    const float* __restrict__ in_proj_w, // (32, 8)
    const float* __restrict__ conv_w,    // (16, 4)
    const float* __restrict__ conv_b,    // (16)
    const float* __restrict__ x_proj_w,  // (33, 16)
    const float* __restrict__ dt_proj_w, // (16, 1)
    const float* __restrict__ dt_proj_b, // (16)
    const float* __restrict__ A_log,     // (16, 16)
    const float* __restrict__ Dp,        // (16)
    const float* __restrict__ out_proj_w,// (8, 16)
    const float* __restrict__ fc_w,      // (12, 2000)
    const float* __restrict__ fc_b,      // (12)
    float* __restrict__ out)             // (B, 12)
{
    __shared__ __align__(16) __half2 s_bc [2][16 * ST];
    __shared__ __align__(16) __half2 s_dlu[2][16 * ST];
    __shared__ __align__(16) __half  s_sz [2][16 * ST];

    const int tid  = threadIdx.x;
    const int p    = tid >> 8;
    const int tid8 = tid & 255;
    const int b0   = blockIdx.x * 2;

    // ---- Phase 0: stage x for BOTH problems coalesced (float4)
    {
        float4* s_xf4 = (float4*)s_dlu[0];
        const float4* __restrict__ xb4 =
            (const float4*)(x + (size_t)b0 * (8 * SEQ));
        for (int i = tid; i < 1000; i += 512) s_xf4[i] = xb4[i];
    }
    __syncthreads();

    // ---- Phase 1: x_in[d*ST+t] -> s_bc(f32) ; silu(z) -> s_sz   (r12 form)
    {
        float* s_f  = (float*)s_bc[p];
        const float* s_xf = (const float*)s_dlu[0] + p * (8 * SEQ);
        const int d  = tid8 & 15;
        const int t0 = tid8 >> 4;
        float w1[8], w2[8];
        #pragma unroll
        for (int m = 0; m < 8; ++m) {
            w1[m] = in_proj_w[d * 8 + m];
            w2[m] = in_proj_w[(16 + d) * 8 + m];
        }
        #pragma unroll
        for (int i = 0; i < 16; ++i) {
            int t = t0 + i * 16;
            if (t < SEQ) {
                float acc = 0.f, z = 0.f;
                #pragma unroll
                for (int m = 0; m < 8; ++m) {
                    float xv = s_xf[m * SEQ + t];
                    acc = fmaf(w1[m], xv, acc);
                    z   = fmaf(w2[m], xv, z);
                }
                s_f[d * ST + t] = acc;
                s_sz[p][d * ST + t] = __float2half(z / (1.f + __expf(-z)));
            }
        }
    }
    __syncthreads();

    // ---- Phase 2: causal conv(k=4)+SiLU -> u into s_dlu[p][d*ST+t].y (r12)
    {
        const float* s_f = (const float*)s_bc[p];
        const int d  = tid8 & 15;
        const int t0 = tid8 >> 4;
        float cw[4];
        #pragma unroll
        for (int k = 0; k < 4; ++k) cw[k] = conv_w[d * 4 + k];
        const float cb = conv_b[d];
        #pragma unroll
        for (int i = 0; i < 16; ++i) {
            int t = t0 + i * 16;
            if (t < SEQ) {
                float acc = cb;
                #pragma unroll
                for (int k = 0; k < 4; ++k) {
                    int tt = t + k - 3;
                    if (tt >= 0) acc = fmaf(cw[k], s_f[d * ST + tt], acc);
                }
                float sg = 1.f / (1.f + __expf(-acc));
                s_dlu[p][d * ST + t].y = __float2half(acc * sg);
            }
        }
    }
    __syncthreads();

    // ---- Phase 3 (MFMA): per 16-t tile, D = u(16t x 16d) * W(16d x 16col)
    // via v_mfma_f32_16x16x16f16 (fragment map verified r12).
    {
        const int wave = tid8 >> 6;       // 0..3
        const int l    = tid8 & 63;
        const int rowc = l & 15;          // A-row (t_local) AND D-col (state)
        const int kg   = l >> 4;          // k-group

        half4v wB, wC, wD;
        #pragma unroll
        for (int i = 0; i < 4; ++i) {
            wB[i] = (_Float16)x_proj_w[(1  + rowc) * 16 + 4 * kg + i];
            wC[i] = (_Float16)x_proj_w[(17 + rowc) * 16 + 4 * kg + i];
            wD[i] = (_Float16)x_proj_w[4 * kg + i];
        }
        const float dtw_c = dt_proj_w[rowc];
        const float dtb_c = dt_proj_b[rowc];
        const float4v zero4 = {0.f, 0.f, 0.f, 0.f};
        const unsigned int* __restrict__ dlu_w = (const unsigned int*)s_dlu[p];

        for (int tile = wave; tile < 16; tile += 4) {
            const int t0 = tile * 16;
            unsigned int w0 = dlu_w[(4 * kg + 0) * ST + t0 + rowc];
            unsigned int w1 = dlu_w[(4 * kg + 1) * ST + t0 + rowc];
            unsigned int w2 = dlu_w[(4 * kg + 2) * ST + t0 + rowc];
            unsigned int w3 = dlu_w[(4 * kg + 3) * ST + t0 + rowc];
            union { unsigned int u[2]; half4v h; } A;
            A.u[0] = (w0 >> 16) | (w1 & 0xFFFF0000u);
            A.u[1] = (w2 >> 16) | (w3 & 0xFFFF0000u);

            float4v dB = __builtin_amdgcn_mfma_f32_16x16x16f16(A.h, wB, zero4, 0, 0, 0);
            float4v dC = __builtin_amdgcn_mfma_f32_16x16x16f16(A.h, wC, zero4, 0, 0, 0);
            float4v dT = __builtin_amdgcn_mfma_f32_16x16x16f16(A.h, wD, zero4, 0, 0, 0);

            const int tb = t0 + kg * 4;
            if (tb <= 248) {
                __half2 h0 = __floats2half2_rn(dB[0], dC[0]);
                __half2 h1 = __floats2half2_rn(dB[1], dC[1]);
                __half2 h2 = __floats2half2_rn(dB[2], dC[2]);
                __half2 h3 = __floats2half2_rn(dB[3], dC[3]);
                float4 wv;
                wv.x = h2_as_f(h0); wv.y = h2_as_f(h1);
                wv.z = h2_as_f(h2); wv.w = h2_as_f(h3);
                *reinterpret_cast<float4*>(s_bc[p] + rowc * ST + tb) = wv;
            }
            #pragma unroll
            for (int r = 0; r < 4; ++r) {
                int t = tb + r;
                if (t < SEQ) {
                    float v  = fmaf(dT[r], dtw_c, dtb_c);
                    float dl = (v > 20.f) ? v : __logf(1.f + __expf(v));
                    s_dlu[p][rowc * ST + t].x = __float2half(dl);
                }
            }
        }
    }
    __syncthreads();

    // ---- Phase 4: scan, fold-4: ONE wave per problem (tid<128).
    // lane = 16d x 4 s-lanes; lane owns states s2, s2+4, s2+8, s2+12.
    // Reduce = 2 quad-local DPP stages. 2-deep software pipeline: named A/B
    // 4t register batches; loads issue before the aliasing y-stores.
    if (tid < 128) {
        const int sp = tid >> 6;          // wave 0 -> problem 0, wave 1 -> p1
        const int l  = tid & 63;
        const int d  = l >> 2;
        const int s2 = l & 3;
        const float LOG2E = 1.4426950408889634f;
        const float A20 = -__expf(A_log[d * 16 + s2])      * LOG2E;
        const float A21 = -__expf(A_log[d * 16 + s2 + 4])  * LOG2E;
        const float A22 = -__expf(A_log[d * 16 + s2 + 8])  * LOG2E;
        const float A23 = -__expf(A_log[d * 16 + s2 + 12]) * LOG2E;
        const float Dd  = Dp[d];
        const __half2* __restrict__ dlu_p = s_dlu[sp] + d * ST;
        const __half2* __restrict__ bc0_p = s_bc [sp] + s2 * ST;
        const __half2* __restrict__ bc1_p = s_bc [sp] + (s2 + 4) * ST;
        const __half2* __restrict__ bc2_p = s_bc [sp] + (s2 + 8) * ST;
        const __half2* __restrict__ bc3_p = s_bc [sp] + (s2 + 12) * ST;
        const __half*  __restrict__ sz_p  = (const __half*)s_sz[sp] + d * ST;
        float* __restrict__ y_p = (float*)s_dlu[sp] + d * ST;
        float h0 = 0.f, h1 = 0.f, h2 = 0.f, h3 = 0.f;

        float4 A_du, A_b0, A_b1, A_b2, A_b3;
        float4 B_du, B_b0, B_b1, B_b2, B_b3;
        float2 A_sz, B_sz;

#define SCAN_LOAD(buf, tt) do { \
        buf##_du = *reinterpret_cast<const float4*>(dlu_p + (tt)); \
        buf##_b0 = *reinterpret_cast<const float4*>(bc0_p + (tt)); \
        buf##_b1 = *reinterpret_cast<const float4*>(bc1_p + (tt)); \
        buf##_b2 = *reinterpret_cast<const float4*>(bc2_p + (tt)); \
        buf##_b3 = *reinterpret_cast<const float4*>(bc3_p + (tt)); \
        buf##_sz = *reinterpret_cast<const float2*>(sz_p + (tt)); } while (0)

#define SCAN_COMPUTE(buf, tt) do { \
        float fdu[4] = {buf##_du.x, buf##_du.y, buf##_du.z, buf##_du.w}; \
        float fb0[4] = {buf##_b0.x, buf##_b0.y, buf##_b0.z, buf##_b0.w}; \
        float fb1[4] = {buf##_b1.x, buf##_b1.y, buf##_b1.z, buf##_b1.w}; \
        float fb2[4] = {buf##_b2.x, buf##_b2.y, buf##_b2.z, buf##_b2.w}; \
        float fb3[4] = {buf##_b3.x, buf##_b3.y, buf##_b3.z, buf##_b3.w}; \
        float2 szl = __half22float2(f_as_h2(buf##_sz.x)); \
        float2 szh = __half22float2(f_as_h2(buf##_sz.y)); \
        float fsz[4] = {szl.x, szl.y, szh.x, szh.y}; \
        float yv[4]; \
        _Pragma("unroll") \
        for (int q = 0; q < 4; ++q) { \
            float2 du = __half22float2(f_as_h2(fdu[q])); \
            float2 b0 = __half22float2(f_as_h2(fb0[q])); \
            float2 b1 = __half22float2(f_as_h2(fb1[q])); \
            float2 b2 = __half22float2(f_as_h2(fb2[q])); \
            float2 b3 = __half22float2(f_as_h2(fb3[q])); \
            float dlu = du.x * du.y; \
            h0 = fmaf(exp2f(du.x * A20), h0, dlu * b0.x); \
            h1 = fmaf(exp2f(du.x * A21), h1, dlu * b1.x); \
            h2 = fmaf(exp2f(du.x * A22), h2, dlu * b2.x); \
            h3 = fmaf(exp2f(du.x * A23), h3, dlu * b3.x); \
            float r = h0 * b0.y; \
            r = fmaf(h1, b1.y, r); \
            r = fmaf(h2, b2.y, r); \
            r = fmaf(h3, b3.y, r); \
            r = dpp_add<0xB1>(r); \
            r = dpp_add<0x4E>(r); \
            yv[q] = fmaf(du.y, Dd, r) * fsz[q]; \
        } \
        if (s2 == 0) { \
            float4 y4; y4.x = yv[0]; y4.y = yv[1]; y4.z = yv[2]; y4.w = yv[3]; \
            *reinterpret_cast<float4*>(y_p + (tt)) = y4; \
        } } while (0)

        SCAN_LOAD(A, 0);
        for (int t = 0; t < 240; t += 8) {
            SCAN_LOAD(B, t + 4);
            SCAN_COMPUTE(A, t);
            SCAN_LOAD(A, t + 8);
            SCAN_COMPUTE(B, t + 4);
        }
        SCAN_LOAD(B, 244);
        SCAN_COMPUTE(A, 240);
        SCAN_COMPUTE(B, 244);
#undef SCAN_LOAD
#undef SCAN_COMPUTE
        {   // tail t = 248, 249
            float2 duv2 = *reinterpret_cast<const float2*>(dlu_p + 248);
            float2 b0v  = *reinterpret_cast<const float2*>(bc0_p + 248);
            float2 b1v  = *reinterpret_cast<const float2*>(bc1_p + 248);
            float2 b2v  = *reinterpret_cast<const float2*>(bc2_p + 248);
            float2 b3v  = *reinterpret_cast<const float2*>(bc3_p + 248);
            float2 szf  = __half22float2(*reinterpret_cast<const __half2*>(sz_p + 248));
            float fdu[2] = {duv2.x, duv2.y};
            float fb0[2] = {b0v.x, b0v.y};
            float fb1[2] = {b1v.x, b1v.y};
            float fb2[2] = {b2v.x, b2v.y};
            float fb3[2] = {b3v.x, b3v.y};
            float fsz[2] = {szf.x, szf.y};
            float yv[2];
            #pragma unroll
            for (int q = 0; q < 2; ++q) {
                float2 du = __half22float2(f_as_h2(fdu[q]));
                float2 b0 = __half22float2(f_as_h2(fb0[q]));
                float2 b1 = __half22float2(f_as_h2(fb1[q]));
                float2 b2 = __half22float2(f_as_h2(fb2[q]));
                float2 b3 = __half22float2(f_as_h2(fb3[q]));
                float dlu = du.x * du.y;
                h0 = fmaf(exp2f(du.x * A20), h0, dlu * b0.x);
                h1 = fmaf(exp2f(du.x * A21), h1, dlu * b1.x);
                h2 = fmaf(exp2f(du.x * A22), h2, dlu * b2.x);
                h3 = fmaf(exp2f(du.x * A23), h3, dlu * b3.x);
                float r = h0 * b0.y;
                r = fmaf(h1, b1.y, r);
                r = fmaf(h2, b2.y, r);
                r = fmaf(h3, b3.y, r);
                r = dpp_add<0xB1>(r);
                r = dpp_add<0x4E>(r);
                yv[q] = fmaf(du.y, Dd, r) * fsz[q];
            }
            if (s2 == 0) {
                float2 y2; y2.x = yv[0]; y2.y = yv[1];
                *reinterpret_cast<float2*>(y_p + 248) = y2;
            }
        }
    }
    __syncthreads();

    // ---- Phase 5b: out2000[t*8+j] = sum_d y[d,t]*out_proj_w[j,d]
    {
        float* s_f  = (float*)s_bc[p];
        const float* s_yf = (const float*)s_dlu[p];
        const int j = tid8 & 7;
        float w[16];
        #pragma unroll
        for (int d2 = 0; d2 < 16; ++d2) w[d2] = out_proj_w[j * 16 + d2];
        for (int t0 = (tid8 >> 3) * 4; t0 < SEQ; t0 += 128) {
            float a0 = 0.f, a1 = 0.f, a2 = 0.f, a3 = 0.f;
            #pragma unroll
            for (int d2 = 0; d2 < 16; ++d2) {
                float4 y4 = *reinterpret_cast<const float4*>(s_yf + d2 * ST + t0);
                a0 = fmaf(w[d2], y4.x, a0);
                a1 = fmaf(w[d2], y4.y, a1);
                a2 = fmaf(w[d2], y4.z, a2);
                a3 = fmaf(w[d2], y4.w, a3);
            }
            s_f[(t0 + 0) * 8 + j] = a0;
            s_f[(t0 + 1) * 8 + j] = a1;
            if (t0 + 2 < SEQ) s_f[(t0 + 2) * 8 + j] = a2;
            if (t0 + 3 < SEQ) s_f[(t0 + 3) * 8 + j] = a3;
        }
    }
    __syncthreads();

    // ---- Phase 6: logits[c] = out2000 . fc_w[c,:] + fc_b[c]  (float4 loads)
    {
        float* s_yf = (float*)s_dlu[p];
        float p_[NCLS];
        #pragma unroll
        for (int c = 0; c < NCLS; ++c) p_[c] = 0.f;
        const float4* fw4 = (const float4*)fc_w;
        const float4* sf4 = (const float4*)s_bc[p];
        for (int q = tid8; q < 500; q += 256) {
            float4 f = sf4[q];
            #pragma unroll
            for (int c = 0; c < NCLS; ++c) {
                float4 wv = fw4[c * 500 + q];
                p_[c] += f.x * wv.x + f.y * wv.y + f.z * wv.z + f.w * wv.w;
            }
        }
        #pragma unroll
        for (int c = 0; c < NCLS; ++c) {
            float v = p_[c];
            v = dpp_add<0xB1>(v);
            v = dpp_add<0x4E>(v);
            v = dpp_add<0x141>(v);
            v = dpp_add<0x140>(v);
            v += __shfl_xor(v, 16);
            v += __shfl_xor(v, 32);
            p_[c] = v;
        }
        const int wave = tid8 >> 6;
        const int lane = tid8 & 63;
        __syncthreads();
        if (lane == 0) {
            #pragma unroll
            for (int c = 0; c < NCLS; ++c) s_yf[wave * NCLS + c] = p_[c];
        }
        __syncthreads();
        if (tid8 < NCLS) {
            float v = s_yf[tid8] + s_yf[NCLS + tid8] + s_yf[2 * NCLS + tid8] +
                      s_yf[3 * NCLS + tid8] + fc_b[tid8];
            out[(size_t)(b0 + p) * NCLS + tid8] = v;
        }
    }
}

extern "C" void kernel_launch(void* const* d_in, const int* in_sizes, int n_in,
                              void* d_out, int out_size, void* d_ws, size_t ws_size,
                              hipStream_t stream) {
    const float* x          = (const float*)d_in[0];
    const float* in_proj_w  = (const float*)d_in[1];
    const float* conv_w     = (const float*)d_in[2];
    const float* conv_b     = (const float*)d_in[3];
    const float* x_proj_w   = (const float*)d_in[4];
    const float* dt_proj_w  = (const float*)d_in[5];
    const float* dt_proj_b  = (const float*)d_in[6];
    const float* A_log      = (const float*)d_in[7];
    const float* Dp         = (const float*)d_in[8];
    const float* out_proj_w = (const float*)d_in[9];
    const float* fc_w       = (const float*)d_in[10];
    const float* fc_b       = (const float*)d_in[11];
    float* out = (float*)d_out;

    const int batch = in_sizes[0] / (8 * SEQ);  // 1024
    mamba_cls_kernel<<<batch / 2, 512, 0, stream>>>(
        x, in_proj_w, conv_w, conv_b, x_proj_w, dt_proj_w, dt_proj_b,
        A_log, Dp, out_proj_w, fc_w, fc_b, out);
}

// Round 16
// 61.784 us; speedup vs baseline: 1.1523x; 1.1523x over previous
//
#include <hip/hip_runtime.h>
#include <hip/hip_fp16.h>
#include <math.h>

#define SEQ 250
#define ST  252      // padded t-stride: rows 16B-aligned (ST*4 = 1008 = 63*16)
#define NCLS 12

typedef __attribute__((ext_vector_type(4))) _Float16 half4v;
typedef __attribute__((ext_vector_type(4))) float    float4v;

// Butterfly add via DPP (zero DS-pipe ops).
// 0xB1=quad_perm xor1; 0x4E=quad_perm xor2; 0x141=row_half_mirror (lane^7,
// valid once quad-constant); 0x140=row_mirror (lane^15, once 8-group-constant).
template<int CTRL>
__device__ __forceinline__ float dpp_add(float v) {
    int t = __builtin_amdgcn_update_dpp(0, __float_as_int(v), CTRL, 0xF, 0xF, true);
    return v + __int_as_float(t);
}

__device__ __forceinline__ __half2 f_as_h2(float f) {
    union { float f; __half2 h; } u; u.f = f; return u.h;
}
__device__ __forceinline__ float h2_as_f(__half2 h) {
    union { __half2 h; float f; } u; u.h = h; return u.f;
}

// 512 threads, TWO batch elements per block.
// LDS: 2 x (s_bc 16128 + s_dlu 16128 + s_sz 8064) = 80,640 B -> 2 blocks/CU.
// r4-r6: no register live ranges across the scan (spills -> 45 MB scratch).
// r11/r12: matrix pipe takes the x_proj projection (ph3).
// r13: ph1-MFMA regressed (gather+cvt overhead) -> ph1/ph2 stay scalar.
// r15 lesson: fold-4 scan (1 wave/problem) is latency-exposed (VALUBusy
// 69->46) -> fold-2 (2 waves/problem) is the right point. r16: fold-2 scan
// with hand-unrolled A/B ping-pong pipeline (loads issue one 8t batch ahead,
// in program order above the aliasing y-stores).
__global__ __launch_bounds__(512)
void mamba_cls_kernel(
    const float* __restrict__ x,         // (B, 8, 250)
    const float* __restrict__ in_proj_w, // (32, 8)
    const float* __restrict__ conv_w,    // (16, 4)
    const float* __restrict__ conv_b,    // (16)
    const float* __restrict__ x_proj_w,  // (33, 16)
    const float* __restrict__ dt_proj_w, // (16, 1)
    const float* __restrict__ dt_proj_b, // (16)
    const float* __restrict__ A_log,     // (16, 16)
    const float* __restrict__ Dp,        // (16)
    const float* __restrict__ out_proj_w,// (8, 16)
    const float* __restrict__ fc_w,      // (12, 2000)
    const float* __restrict__ fc_b,      // (12)
    float* __restrict__ out)             // (B, 12)
{
    __shared__ __align__(16) __half2 s_bc [2][16 * ST];
    __shared__ __align__(16) __half2 s_dlu[2][16 * ST];
    __shared__ __align__(16) __half  s_sz [2][16 * ST];

    const int tid  = threadIdx.x;
    const int p    = tid >> 8;
    const int tid8 = tid & 255;
    const int b0   = blockIdx.x * 2;

    // ---- Phase 0: stage x for BOTH problems coalesced (float4)
    {
        float4* s_xf4 = (float4*)s_dlu[0];
        const float4* __restrict__ xb4 =
            (const float4*)(x + (size_t)b0 * (8 * SEQ));
        for (int i = tid; i < 1000; i += 512) s_xf4[i] = xb4[i];
    }
    __syncthreads();

    // ---- Phase 1: x_in[d*ST+t] -> s_bc(f32) ; silu(z) -> s_sz   (r12 form)
    {
        float* s_f  = (float*)s_bc[p];
        const float* s_xf = (const float*)s_dlu[0] + p * (8 * SEQ);
        const int d  = tid8 & 15;
        const int t0 = tid8 >> 4;
        float w1[8], w2[8];
        #pragma unroll
        for (int m = 0; m < 8; ++m) {
            w1[m] = in_proj_w[d * 8 + m];
            w2[m] = in_proj_w[(16 + d) * 8 + m];
        }
        #pragma unroll
        for (int i = 0; i < 16; ++i) {
            int t = t0 + i * 16;
            if (t < SEQ) {
                float acc = 0.f, z = 0.f;
                #pragma unroll
                for (int m = 0; m < 8; ++m) {
                    float xv = s_xf[m * SEQ + t];
                    acc = fmaf(w1[m], xv, acc);
                    z   = fmaf(w2[m], xv, z);
                }
                s_f[d * ST + t] = acc;
                s_sz[p][d * ST + t] = __float2half(z / (1.f + __expf(-z)));
            }
        }
    }
    __syncthreads();

    // ---- Phase 2: causal conv(k=4)+SiLU -> u into s_dlu[p][d*ST+t].y (r12)
    {
        const float* s_f = (const float*)s_bc[p];
        const int d  = tid8 & 15;
        const int t0 = tid8 >> 4;
        float cw[4];
        #pragma unroll
        for (int k = 0; k < 4; ++k) cw[k] = conv_w[d * 4 + k];
        const float cb = conv_b[d];
        #pragma unroll
        for (int i = 0; i < 16; ++i) {
            int t = t0 + i * 16;
            if (t < SEQ) {
                float acc = cb;
                #pragma unroll
                for (int k = 0; k < 4; ++k) {
                    int tt = t + k - 3;
                    if (tt >= 0) acc = fmaf(cw[k], s_f[d * ST + tt], acc);
                }
                float sg = 1.f / (1.f + __expf(-acc));
                s_dlu[p][d * ST + t].y = __float2half(acc * sg);
            }
        }
    }
    __syncthreads();

    // ---- Phase 3 (MFMA): per 16-t tile, D = u(16t x 16d) * W(16d x 16col)
    // via v_mfma_f32_16x16x16f16 (fragment map verified r12).
    {
        const int wave = tid8 >> 6;       // 0..3
        const int l    = tid8 & 63;
        const int rowc = l & 15;          // A-row (t_local) AND D-col (state)
        const int kg   = l >> 4;          // k-group

        half4v wB, wC, wD;
        #pragma unroll
        for (int i = 0; i < 4; ++i) {
            wB[i] = (_Float16)x_proj_w[(1  + rowc) * 16 + 4 * kg + i];
            wC[i] = (_Float16)x_proj_w[(17 + rowc) * 16 + 4 * kg + i];
            wD[i] = (_Float16)x_proj_w[4 * kg + i];
        }
        const float dtw_c = dt_proj_w[rowc];
        const float dtb_c = dt_proj_b[rowc];
        const float4v zero4 = {0.f, 0.f, 0.f, 0.f};
        const unsigned int* __restrict__ dlu_w = (const unsigned int*)s_dlu[p];

        for (int tile = wave; tile < 16; tile += 4) {
            const int t0 = tile * 16;
            // A-frag: u[t0+rowc][4kg+i] = high half of {dl,u} word
            unsigned int w0 = dlu_w[(4 * kg + 0) * ST + t0 + rowc];
            unsigned int w1 = dlu_w[(4 * kg + 1) * ST + t0 + rowc];
            unsigned int w2 = dlu_w[(4 * kg + 2) * ST + t0 + rowc];
            unsigned int w3 = dlu_w[(4 * kg + 3) * ST + t0 + rowc];
            union { unsigned int u[2]; half4v h; } A;
            A.u[0] = (w0 >> 16) | (w1 & 0xFFFF0000u);
            A.u[1] = (w2 >> 16) | (w3 & 0xFFFF0000u);

            float4v dB = __builtin_amdgcn_mfma_f32_16x16x16f16(A.h, wB, zero4, 0, 0, 0);
            float4v dC = __builtin_amdgcn_mfma_f32_16x16x16f16(A.h, wC, zero4, 0, 0, 0);
            float4v dT = __builtin_amdgcn_mfma_f32_16x16x16f16(A.h, wD, zero4, 0, 0, 0);

            const int tb = t0 + kg * 4;   // first of this lane's 4 t's
            if (tb <= 248) {              // words tb..tb+3 <= 251 (pad ok)
                __half2 h0 = __floats2half2_rn(dB[0], dC[0]);
                __half2 h1 = __floats2half2_rn(dB[1], dC[1]);
                __half2 h2 = __floats2half2_rn(dB[2], dC[2]);
                __half2 h3 = __floats2half2_rn(dB[3], dC[3]);
                float4 wv;
                wv.x = h2_as_f(h0); wv.y = h2_as_f(h1);
                wv.z = h2_as_f(h2); wv.w = h2_as_f(h3);
                *reinterpret_cast<float4*>(s_bc[p] + rowc * ST + tb) = wv;
            }
            #pragma unroll
            for (int r = 0; r < 4; ++r) {
                int t = tb + r;
                if (t < SEQ) {
                    float v  = fmaf(dT[r], dtw_c, dtb_c);
                    float dl = (v > 20.f) ? v : __logf(1.f + __expf(v));
                    s_dlu[p][rowc * ST + t].x = __float2half(dl);
                }
            }
        }
    }
    __syncthreads();

    // ---- Phase 4: scan, s-folded x2 (fold-2: 2 waves/problem), 8t batches
    // with A/B ping-pong pipeline: each batch's 8 DS loads issue one full
    // batch ahead of use, above the aliasing y-stores (disjoint addresses;
    // same-wave DS ordering). Active: tid<256 (waves 0-3).
    if (tid < 256) {
        const int sp   = tid >> 7;
        const int i7   = tid & 127;
        const int d    = i7 >> 3;
        const int s2   = i7 & 7;
        const float A2a = -__expf(A_log[d * 16 + s2])     * 1.4426950408889634f;
        const float A2b = -__expf(A_log[d * 16 + s2 + 8]) * 1.4426950408889634f;
        const float Dd  = Dp[d];
        const __half2* __restrict__ dlu_p = s_dlu[sp] + d * ST;
        const __half2* __restrict__ bca_p = s_bc [sp] + s2 * ST;
        const __half2* __restrict__ bcb_p = s_bc [sp] + (s2 + 8) * ST;
        const __half*  __restrict__ sz_p  = (const __half*)s_sz[sp] + d * ST;
        float* __restrict__ y_p = (float*)s_dlu[sp] + d * ST;
        float ha = 0.f, hb = 0.f;

        float4 A_du0, A_du1, A_ba0, A_ba1, A_bb0, A_bb1;
        float4 B_du0, B_du1, B_ba0, B_ba1, B_bb0, B_bb1;
        float2 A_sz0, A_sz1, B_sz0, B_sz1;

#define SCAN_LOAD(buf, tt) do { \
        buf##_du0 = *reinterpret_cast<const float4*>(dlu_p + (tt)); \
        buf##_du1 = *reinterpret_cast<const float4*>(dlu_p + (tt) + 4); \
        buf##_ba0 = *reinterpret_cast<const float4*>(bca_p + (tt)); \
        buf##_ba1 = *reinterpret_cast<const float4*>(bca_p + (tt) + 4); \
        buf##_bb0 = *reinterpret_cast<const float4*>(bcb_p + (tt)); \
        buf##_bb1 = *reinterpret_cast<const float4*>(bcb_p + (tt) + 4); \
        buf##_sz0 = *reinterpret_cast<const float2*>(sz_p + (tt)); \
        buf##_sz1 = *reinterpret_cast<const float2*>(sz_p + (tt) + 4); } while (0)

#define SCAN_COMPUTE(buf, tt) do { \
        float fdu[8] = {buf##_du0.x, buf##_du0.y, buf##_du0.z, buf##_du0.w, \
                        buf##_du1.x, buf##_du1.y, buf##_du1.z, buf##_du1.w}; \
        float fba[8] = {buf##_ba0.x, buf##_ba0.y, buf##_ba0.z, buf##_ba0.w, \
                        buf##_ba1.x, buf##_ba1.y, buf##_ba1.z, buf##_ba1.w}; \
        float fbb[8] = {buf##_bb0.x, buf##_bb0.y, buf##_bb0.z, buf##_bb0.w, \
                        buf##_bb1.x, buf##_bb1.y, buf##_bb1.z, buf##_bb1.w}; \
        float2 q0 = __half22float2(f_as_h2(buf##_sz0.x)); \
        float2 q1 = __half22float2(f_as_h2(buf##_sz0.y)); \
        float2 q2 = __half22float2(f_as_h2(buf##_sz1.x)); \
        float2 q3 = __half22float2(f_as_h2(buf##_sz1.y)); \
        float fsz[8] = {q0.x, q0.y, q1.x, q1.y, q2.x, q2.y, q3.x, q3.y}; \
        float yv[8]; \
        _Pragma("unroll") \
        for (int q = 0; q < 8; ++q) { \
            float2 du  = __half22float2(f_as_h2(fdu[q])); \
            float2 bca = __half22float2(f_as_h2(fba[q])); \
            float2 bcb = __half22float2(f_as_h2(fbb[q])); \
            float dlu = du.x * du.y; \
            ha = fmaf(exp2f(du.x * A2a), ha, dlu * bca.x); \
            hb = fmaf(exp2f(du.x * A2b), hb, dlu * bcb.x); \
            float r = fmaf(hb, bcb.y, ha * bca.y); \
            r = dpp_add<0xB1>(r); \
            r = dpp_add<0x4E>(r); \
            r = dpp_add<0x141>(r); \
            yv[q] = fmaf(du.y, Dd, r) * fsz[q]; \
        } \
        if (s2 == 0) { \
            float4 y4; \
            y4.x = yv[0]; y4.y = yv[1]; y4.z = yv[2]; y4.w = yv[3]; \
            *reinterpret_cast<float4*>(y_p + (tt)) = y4; \
            y4.x = yv[4]; y4.y = yv[5]; y4.z = yv[6]; y4.w = yv[7]; \
            *reinterpret_cast<float4*>(y_p + (tt) + 4) = y4; \
        } } while (0)

        SCAN_LOAD(A, 0);
        for (int t = 0; t < 240; t += 16) {       // t = 0,16,...,224
            SCAN_LOAD(B, t + 8);
            SCAN_COMPUTE(A, t);
            SCAN_LOAD(A, t + 16);                 // at t=224 loads batch 240
            SCAN_COMPUTE(B, t + 8);
        }
        SCAN_COMPUTE(A, 240);                     // batch 240..247
#undef SCAN_LOAD
#undef SCAN_COMPUTE
        {   // tail t = 248, 249
            float2 duv2 = *reinterpret_cast<const float2*>(dlu_p + 248);
            float2 bca2 = *reinterpret_cast<const float2*>(bca_p + 248);
            float2 bcb2 = *reinterpret_cast<const float2*>(bcb_p + 248);
            float2 szf  = __half22float2(*reinterpret_cast<const __half2*>(sz_p + 248));
            float fdu[2] = {duv2.x, duv2.y};
            float fba[2] = {bca2.x, bca2.y};
            float fbb[2] = {bcb2.x, bcb2.y};
            float fsz[2] = {szf.x, szf.y};
            float yv[2];
            #pragma unroll
            for (int tt = 0; tt < 2; ++tt) {
                float2 du  = __half22float2(f_as_h2(fdu[tt]));
                float2 bca = __half22float2(f_as_h2(fba[tt]));
                float2 bcb = __half22float2(f_as_h2(fbb[tt]));
                float dlu = du.x * du.y;
                ha = fmaf(exp2f(du.x * A2a), ha, dlu * bca.x);
                hb = fmaf(exp2f(du.x * A2b), hb, dlu * bcb.x);
                float r = fmaf(hb, bcb.y, ha * bca.y);
                r = dpp_add<0xB1>(r);
                r = dpp_add<0x4E>(r);
                r = dpp_add<0x141>(r);
                yv[tt] = fmaf(du.y, Dd, r) * fsz[tt];
            }
            if (s2 == 0) {
                float2 y2; y2.x = yv[0]; y2.y = yv[1];
                *reinterpret_cast<float2*>(y_p + 248) = y2;
            }
        }
    }
    __syncthreads();

    // ---- Phase 5b: out2000[t*8+j] = sum_d y[d,t]*out_proj_w[j,d]
    // Mapping: j = tid8&7, 4t-chunk = tid8>>3; y read as b128 per d-row.
    {
        float* s_f  = (float*)s_bc[p];
        const float* s_yf = (const float*)s_dlu[p];
        const int j = tid8 & 7;
        float w[16];
        #pragma unroll
        for (int d2 = 0; d2 < 16; ++d2) w[d2] = out_proj_w[j * 16 + d2];
        for (int t0 = (tid8 >> 3) * 4; t0 < SEQ; t0 += 128) {
            float a0 = 0.f, a1 = 0.f, a2 = 0.f, a3 = 0.f;
            #pragma unroll
            for (int d2 = 0; d2 < 16; ++d2) {
                float4 y4 = *reinterpret_cast<const float4*>(s_yf + d2 * ST + t0);
                a0 = fmaf(w[d2], y4.x, a0);
                a1 = fmaf(w[d2], y4.y, a1);
                a2 = fmaf(w[d2], y4.z, a2);
                a3 = fmaf(w[d2], y4.w, a3);
            }
            s_f[(t0 + 0) * 8 + j] = a0;
            s_f[(t0 + 1) * 8 + j] = a1;
            if (t0 + 2 < SEQ) s_f[(t0 + 2) * 8 + j] = a2;
            if (t0 + 3 < SEQ) s_f[(t0 + 3) * 8 + j] = a3;
        }
    }
    __syncthreads();

    // ---- Phase 6: logits[c] = out2000 . fc_w[c,:] + fc_b[c]  (float4 loads)
    {
        float* s_yf = (float*)s_dlu[p];
        float p_[NCLS];
        #pragma unroll
        for (int c = 0; c < NCLS; ++c) p_[c] = 0.f;
        const float4* fw4 = (const float4*)fc_w;
        const float4* sf4 = (const float4*)s_bc[p];
        for (int q = tid8; q < 500; q += 256) {
            float4 f = sf4[q];
            #pragma unroll
            for (int c = 0; c < NCLS; ++c) {
                float4 wv = fw4[c * 500 + q];
                p_[c] += f.x * wv.x + f.y * wv.y + f.z * wv.z + f.w * wv.w;
            }
        }
        #pragma unroll
        for (int c = 0; c < NCLS; ++c) {
            float v = p_[c];
            v = dpp_add<0xB1>(v);
            v = dpp_add<0x4E>(v);
            v = dpp_add<0x141>(v);
            v = dpp_add<0x140>(v);
            v += __shfl_xor(v, 16);
            v += __shfl_xor(v, 32);
            p_[c] = v;
        }
        const int wave = tid8 >> 6;
        const int lane = tid8 & 63;
        __syncthreads();
        if (lane == 0) {
            #pragma unroll
            for (int c = 0; c < NCLS; ++c) s_yf[wave * NCLS + c] = p_[c];
        }
        __syncthreads();
        if (tid8 < NCLS) {
            float v = s_yf[tid8] + s_yf[NCLS + tid8] + s_yf[2 * NCLS + tid8] +
                      s_yf[3 * NCLS + tid8] + fc_b[tid8];
            out[(size_t)(b0 + p) * NCLS + tid8] = v;
        }
    }
}

extern "C" void kernel_launch(void* const* d_in, const int* in_sizes, int n_in,
                              void* d_out, int out_size, void* d_ws, size_t ws_size,
                              hipStream_t stream) {
    const float* x          = (const float*)d_in[0];
    const float* in_proj_w  = (const float*)d_in[1];
    const float* conv_w     = (const float*)d_in[2];
    const float* conv_b     = (const float*)d_in[3];
    const float* x_proj_w   = (const float*)d_in[4];
    const float* dt_proj_w  = (const float*)d_in[5];
    const float* dt_proj_b  = (const float*)d_in[6];
    const float* A_log      = (const float*)d_in[7];
    const float* Dp         = (const float*)d_in[8];
    const float* out_proj_w = (const float*)d_in[9];
    const float* fc_w       = (const float*)d_in[10];
    const float* fc_b       = (const float*)d_in[11];
    float* out = (float*)d_out;

    const int batch = in_sizes[0] / (8 * SEQ);  // 1024
    mamba_cls_kernel<<<batch / 2, 512, 0, stream>>>(
        x, in_proj_w, conv_w, conv_b, x_proj_w, dt_proj_w, dt_proj_b,
        A_log, Dp, out_proj_w, fc_w, fc_b, out);
}